// Round 4
// baseline (615.761 us; speedup 1.0000x reference)
//
#include <hip/hip_runtime.h>

#define RES 256
#define THRESH 0.01f
#define GRID_VOX (RES * RES * RES)          // 16,777,216 voxels
#define BITMAP_WORDS (GRID_VOX / 32)        // 524,288 uints = 2 MB

typedef float vf4 __attribute__((ext_vector_type(4)));

__device__ __forceinline__ int voxel_coord(float p) {
    // Replicate reference rounding exactly:
    // pts = -1 + p*2 ; coord = ((pts+1)/2)*256 ; trunc ; clamp
    float a = -1.0f + p * 2.0f;              // mul by 2 exact; one rounding
    float c = ((a + 1.0f) * 0.5f) * 256.0f;  // one rounding at (a+1); scalings exact
    int v = (int)c;
    v = v < 0 ? 0 : v;
    v = v > (RES - 1) ? (RES - 1) : v;
    return v;
}

// Phase 1: scatter single bits into a 2 MB bitmap via atomicOr.
// 2 MB stays resident in every L2 (4 MiB/XCD) -> no line thrash to HBM.
__global__ void occ_scatter_bits(const vf4* __restrict__ pts4,
                                 const vf4* __restrict__ dens4,
                                 unsigned int* __restrict__ bitmap, int n4) {
    int t = blockIdx.x * blockDim.x + threadIdx.x;
    int stride = gridDim.x * blockDim.x;
    for (int i = t; i < n4; i += stride) {
        vf4 p0 = __builtin_nontemporal_load(&pts4[3 * i + 0]);
        vf4 p1 = __builtin_nontemporal_load(&pts4[3 * i + 1]);
        vf4 p2 = __builtin_nontemporal_load(&pts4[3 * i + 2]);
        vf4 d  = __builtin_nontemporal_load(&dens4[i]);

        float px[4] = {p0.x, p0.w, p1.z, p2.y};
        float py[4] = {p0.y, p1.x, p1.w, p2.z};
        float pz[4] = {p0.z, p1.y, p2.x, p2.w};
        float dd[4] = {d.x, d.y, d.z, d.w};

        #pragma unroll
        for (int k = 0; k < 4; ++k) {
            if (dd[k] > THRESH) {
                int ix = voxel_coord(px[k]);
                int iy = voxel_coord(py[k]);
                int iz = voxel_coord(pz[k]);
                unsigned int v = ((unsigned)ix << 16) | ((unsigned)iy << 8) | (unsigned)iz;
                atomicOr(&bitmap[v >> 5], 1u << (v & 31u));
            }
        }
    }
}

// Phase 2: bitmap -> floats. One thread per float4 (4 voxels); 8 threads
// share one bitmap word (L1 broadcast). Fully coalesced 64 MB store,
// doubles as the zero-init of d_out.
__global__ void occ_expand_bits(const unsigned int* __restrict__ bitmap,
                                float4* __restrict__ grid4) {
    int j = blockIdx.x * blockDim.x + threadIdx.x;   // float4 index
    unsigned int w = bitmap[j >> 3];
    unsigned int bits = (w >> ((j & 7) * 4)) & 0xFu;
    float4 f;
    f.x = (bits & 1u) ? 1.0f : 0.0f;
    f.y = (bits & 2u) ? 1.0f : 0.0f;
    f.z = (bits & 4u) ? 1.0f : 0.0f;
    f.w = (bits & 8u) ? 1.0f : 0.0f;
    __builtin_nontemporal_store(f.x, &((float*)grid4)[4 * j + 0]);
    __builtin_nontemporal_store(f.y, &((float*)grid4)[4 * j + 1]);
    __builtin_nontemporal_store(f.z, &((float*)grid4)[4 * j + 2]);
    __builtin_nontemporal_store(f.w, &((float*)grid4)[4 * j + 3]);
}

// Fallback (ws too small): direct float scatter as in round 1.
__global__ void occ_scatter_float(const float4* __restrict__ pts4,
                                  const float4* __restrict__ dens4,
                                  float* __restrict__ grid, int n4) {
    int t = blockIdx.x * blockDim.x + threadIdx.x;
    int stride = gridDim.x * blockDim.x;
    for (int i = t; i < n4; i += stride) {
        float4 p0 = pts4[3 * i + 0];
        float4 p1 = pts4[3 * i + 1];
        float4 p2 = pts4[3 * i + 2];
        float4 d  = dens4[i];
        float px[4] = {p0.x, p0.w, p1.z, p2.y};
        float py[4] = {p0.y, p1.x, p1.w, p2.z};
        float pz[4] = {p0.z, p1.y, p2.x, p2.w};
        float dd[4] = {d.x, d.y, d.z, d.w};
        #pragma unroll
        for (int k = 0; k < 4; ++k) {
            if (dd[k] > THRESH) {
                int ix = voxel_coord(px[k]);
                int iy = voxel_coord(py[k]);
                int iz = voxel_coord(pz[k]);
                grid[((ix * RES) + iy) * RES + iz] = 1.0f;
            }
        }
    }
}

extern "C" void kernel_launch(void* const* d_in, const int* in_sizes, int n_in,
                              void* d_out, int out_size, void* d_ws, size_t ws_size,
                              hipStream_t stream) {
    const float* points    = (const float*)d_in[0];   // [N,3]
    const float* densities = (const float*)d_in[1];   // [N]
    float* grid = (float*)d_out;                      // 256^3 floats

    int n  = in_sizes[1];     // 16,000,000 (divisible by 4)
    int n4 = n / 4;

    if (ws_size >= (size_t)BITMAP_WORDS * sizeof(unsigned int)) {
        unsigned int* bitmap = (unsigned int*)d_ws;
        (void)hipMemsetAsync(d_ws, 0, (size_t)BITMAP_WORDS * sizeof(unsigned int), stream);

        occ_scatter_bits<<<2048, 256, 0, stream>>>(
            (const vf4*)points, (const vf4*)densities, bitmap, n4);

        // GRID_VOX/4 float4 stores: 4,194,304 threads
        occ_expand_bits<<<GRID_VOX / 4 / 256, 256, 0, stream>>>(
            bitmap, (float4*)grid);
    } else {
        (void)hipMemsetAsync(d_out, 0, (size_t)out_size * sizeof(float), stream);
        occ_scatter_float<<<2048, 256, 0, stream>>>(
            (const float4*)points, (const float4*)densities, grid, n4);
    }
}

// Round 5
// 318.552 us; speedup vs baseline: 1.9330x; 1.9330x over previous
//
#include <hip/hip_runtime.h>

#define RES 256
#define THRESH 0.01f
#define GRID_VOX (RES * RES * RES)   // 16,777,216 voxels; byte grid = 16 MB

typedef float vf4 __attribute__((ext_vector_type(4)));
typedef unsigned int u32;
typedef u32 vu4 __attribute__((ext_vector_type(4)));

__device__ __forceinline__ int voxel_coord(float p) {
    // Replicate reference rounding exactly:
    // pts = -1 + p*2 ; coord = ((pts+1)/2)*256 ; trunc ; clamp
    float a = -1.0f + p * 2.0f;              // mul by 2 exact; one rounding
    float c = ((a + 1.0f) * 0.5f) * 256.0f;  // one rounding at (a+1); scalings exact
    int v = (int)c;
    v = v < 0 ? 0 : v;
    v = v > (RES - 1) ? (RES - 1) : v;
    return v;
}

// K1: inputs -> packed records (bit31 = occupied, bits 0..23 = voxel id).
// Fully coalesced 64 MB write; records stay hot in LLC for K2's re-reads.
__global__ void k1_make_records(const vf4* __restrict__ pts4,
                                const vf4* __restrict__ dens4,
                                vu4* __restrict__ recs4, int n4) {
    int t = blockIdx.x * blockDim.x + threadIdx.x;
    int stride = gridDim.x * blockDim.x;
    for (int i = t; i < n4; i += stride) {
        vf4 p0 = __builtin_nontemporal_load(&pts4[3 * i + 0]);
        vf4 p1 = __builtin_nontemporal_load(&pts4[3 * i + 1]);
        vf4 p2 = __builtin_nontemporal_load(&pts4[3 * i + 2]);
        vf4 d  = __builtin_nontemporal_load(&dens4[i]);

        float px[4] = {p0.x, p0.w, p1.z, p2.y};
        float py[4] = {p0.y, p1.x, p1.w, p2.z};
        float pz[4] = {p0.z, p1.y, p2.x, p2.w};
        float dd[4] = {d.x, d.y, d.z, d.w};

        vu4 r;
        #pragma unroll
        for (int k = 0; k < 4; ++k) {
            u32 vox = ((u32)voxel_coord(px[k]) << 16) |
                      ((u32)voxel_coord(py[k]) << 8)  |
                       (u32)voxel_coord(pz[k]);
            u32 rec = vox | (dd[k] > THRESH ? 0x80000000u : 0u);
            r[k] = rec;
        }
        recs4[i] = r;   // regular store (keep LLC-resident for K2)
    }
}

// K2: 8 block-groups (group = blockIdx%8 -> XCD via round-robin dispatch).
// Group s scans ALL records (nt loads) and byte-stores only voxels in its
// 2 MB slice (ix>>5 == s) -> the slice stays resident in that XCD's 4 MiB L2,
// collapsing the scattered-store HBM traffic to the ~16 MB final writeback.
__global__ void k2_slice_scatter(const vu4* __restrict__ recs4,
                                 unsigned char* __restrict__ bgrid, int r4) {
    int s = blockIdx.x & 7;
    int g = (blockIdx.x >> 3) * blockDim.x + threadIdx.x;
    int stride = (gridDim.x >> 3) * blockDim.x;
    for (int j = g; j < r4; j += stride) {
        vu4 r = __builtin_nontemporal_load(&recs4[j]);
        #pragma unroll
        for (int k = 0; k < 4; ++k) {
            u32 rec = r[k];
            if ((rec >> 31) && (int)((rec >> 21) & 7u) == s)
                bgrid[rec & 0x00FFFFFFu] = (unsigned char)1;
        }
    }
}

// K3: byte grid -> float grid (coalesced; doubles as zero-init of d_out).
__global__ void occ_expand(const uint4* __restrict__ bgrid16,
                           float4* __restrict__ grid4) {
    int i = blockIdx.x * blockDim.x + threadIdx.x;  // one thread = 16 voxels
    uint4 w = bgrid16[i];
    unsigned int ws[4] = {w.x, w.y, w.z, w.w};
    #pragma unroll
    for (int q = 0; q < 4; ++q) {
        unsigned int v = ws[q];
        float4 f;
        f.x = (v & 0x000000FFu) ? 1.0f : 0.0f;
        f.y = (v & 0x0000FF00u) ? 1.0f : 0.0f;
        f.z = (v & 0x00FF0000u) ? 1.0f : 0.0f;
        f.w = (v & 0xFF000000u) ? 1.0f : 0.0f;
        grid4[i * 4 + q] = f;
    }
}

// Fallback 1 (ws >= 16 MB): round-3 byte-grid scatter.
__global__ void occ_scatter_bytes(const vf4* __restrict__ pts4,
                                  const vf4* __restrict__ dens4,
                                  unsigned char* __restrict__ bgrid, int n4) {
    int t = blockIdx.x * blockDim.x + threadIdx.x;
    int stride = gridDim.x * blockDim.x;
    for (int i = t; i < n4; i += stride) {
        vf4 p0 = __builtin_nontemporal_load(&pts4[3 * i + 0]);
        vf4 p1 = __builtin_nontemporal_load(&pts4[3 * i + 1]);
        vf4 p2 = __builtin_nontemporal_load(&pts4[3 * i + 2]);
        vf4 d  = __builtin_nontemporal_load(&dens4[i]);
        float px[4] = {p0.x, p0.w, p1.z, p2.y};
        float py[4] = {p0.y, p1.x, p1.w, p2.z};
        float pz[4] = {p0.z, p1.y, p2.x, p2.w};
        float dd[4] = {d.x, d.y, d.z, d.w};
        #pragma unroll
        for (int k = 0; k < 4; ++k) {
            if (dd[k] > THRESH) {
                int ix = voxel_coord(px[k]);
                int iy = voxel_coord(py[k]);
                int iz = voxel_coord(pz[k]);
                bgrid[((ix << 8) | iy) * RES + iz] = (unsigned char)1;
            }
        }
    }
}

// Fallback 2 (tiny ws): round-1 direct float scatter.
__global__ void occ_scatter_float(const float4* __restrict__ pts4,
                                  const float4* __restrict__ dens4,
                                  float* __restrict__ grid, int n4) {
    int t = blockIdx.x * blockDim.x + threadIdx.x;
    int stride = gridDim.x * blockDim.x;
    for (int i = t; i < n4; i += stride) {
        float4 p0 = pts4[3 * i + 0];
        float4 p1 = pts4[3 * i + 1];
        float4 p2 = pts4[3 * i + 2];
        float4 d  = dens4[i];
        float px[4] = {p0.x, p0.w, p1.z, p2.y};
        float py[4] = {p0.y, p1.x, p1.w, p2.z};
        float pz[4] = {p0.z, p1.y, p2.x, p2.w};
        float dd[4] = {d.x, d.y, d.z, d.w};
        #pragma unroll
        for (int k = 0; k < 4; ++k) {
            if (dd[k] > THRESH) {
                int ix = voxel_coord(px[k]);
                int iy = voxel_coord(py[k]);
                int iz = voxel_coord(pz[k]);
                grid[((ix * RES) + iy) * RES + iz] = 1.0f;
            }
        }
    }
}

extern "C" void kernel_launch(void* const* d_in, const int* in_sizes, int n_in,
                              void* d_out, int out_size, void* d_ws, size_t ws_size,
                              hipStream_t stream) {
    const float* points    = (const float*)d_in[0];   // [N,3]
    const float* densities = (const float*)d_in[1];   // [N]
    float* grid = (float*)d_out;                      // 256^3 floats

    int n  = in_sizes[1];     // 16,000,000 (divisible by 16)
    int n4 = n / 4;           // point quads
    int r4 = n / 4;           // record quads (uint4)

    size_t need = (size_t)GRID_VOX + (size_t)n * sizeof(u32);  // 16 MB + 64 MB

    if (ws_size >= need) {
        unsigned char* bgrid = (unsigned char*)d_ws;
        vu4* recs4 = (vu4*)((char*)d_ws + GRID_VOX);

        (void)hipMemsetAsync(d_ws, 0, (size_t)GRID_VOX, stream);

        k1_make_records<<<2048, 256, 0, stream>>>(
            (const vf4*)points, (const vf4*)densities, recs4, n4);

        k2_slice_scatter<<<2048, 256, 0, stream>>>(
            (const vu4*)recs4, bgrid, r4);

        occ_expand<<<GRID_VOX / (16 * 256), 256, 0, stream>>>(
            (const uint4*)bgrid, (float4*)grid);
    } else if (ws_size >= (size_t)GRID_VOX) {
        unsigned char* bgrid = (unsigned char*)d_ws;
        (void)hipMemsetAsync(d_ws, 0, (size_t)GRID_VOX, stream);
        occ_scatter_bytes<<<2048, 256, 0, stream>>>(
            (const vf4*)points, (const vf4*)densities, bgrid, n4);
        occ_expand<<<GRID_VOX / (16 * 256), 256, 0, stream>>>(
            (const uint4*)bgrid, (float4*)grid);
    } else {
        (void)hipMemsetAsync(d_out, 0, (size_t)out_size * sizeof(float), stream);
        occ_scatter_float<<<2048, 256, 0, stream>>>(
            (const float4*)points, (const float4*)densities, grid, n4);
    }
}

// Round 6
// 308.116 us; speedup vs baseline: 1.9985x; 1.0339x over previous
//
#include <hip/hip_runtime.h>

#define RES 256
#define THRESH 0.01f
#define GRID_VOX (RES * RES * RES)     // 16,777,216 voxels; byte grid = 16 MB
#define NBUCK 8                        // one bucket per XCD (ix>>5)
#define CAP 1999872                    // per-bucket capacity (mean 1.98M + ~15 sigma)

typedef float vf4 __attribute__((ext_vector_type(4)));
typedef unsigned int u32;
typedef u32 vu4 __attribute__((ext_vector_type(4)));

__device__ __forceinline__ int voxel_coord(float p) {
    // Replicate reference rounding exactly:
    // pts = -1 + p*2 ; coord = ((pts+1)/2)*256 ; trunc ; clamp
    float a = -1.0f + p * 2.0f;              // mul by 2 exact; one rounding
    float c = ((a + 1.0f) * 0.5f) * 256.0f;  // one rounding at (a+1); scalings exact
    int v = (int)c;
    v = v < 0 ? 0 : v;
    v = v > (RES - 1) ? (RES - 1) : v;
    return v;
}

// K1: inputs -> occupied voxel records, counting-sorted into 8 ix-slice
// buckets. Block-level LDS staging gives coalesced burst writes per bucket.
__global__ void k1_bin_records(const vf4* __restrict__ pts4,
                               const vf4* __restrict__ dens4,
                               u32* __restrict__ buckets,   // 8 x CAP
                               u32* __restrict__ cursors,   // 8
                               int n4) {
    __shared__ u32 s_cnt[NBUCK];
    __shared__ u32 s_off[NBUCK];
    __shared__ u32 s_base[NBUCK];
    __shared__ u32 s_buf[1024];          // <= 256 threads * 4 records

    const int tid = threadIdx.x;
    const int bstride = gridDim.x * blockDim.x;

    for (int base = blockIdx.x * blockDim.x; base < n4; base += bstride) {
        int i = base + tid;
        if (tid < NBUCK) s_cnt[tid] = 0;
        __syncthreads();

        u32 rec[4]; int rb[4]; u32 rrank[4];
        bool rv[4] = {false, false, false, false};

        if (i < n4) {
            vf4 p0 = __builtin_nontemporal_load(&pts4[3 * i + 0]);
            vf4 p1 = __builtin_nontemporal_load(&pts4[3 * i + 1]);
            vf4 p2 = __builtin_nontemporal_load(&pts4[3 * i + 2]);
            vf4 d  = __builtin_nontemporal_load(&dens4[i]);

            float px[4] = {p0.x, p0.w, p1.z, p2.y};
            float py[4] = {p0.y, p1.x, p1.w, p2.z};
            float pz[4] = {p0.z, p1.y, p2.x, p2.w};
            float dd[4] = {d.x, d.y, d.z, d.w};

            #pragma unroll
            for (int k = 0; k < 4; ++k) {
                if (dd[k] > THRESH) {
                    u32 vox = ((u32)voxel_coord(px[k]) << 16) |
                              ((u32)voxel_coord(py[k]) << 8)  |
                               (u32)voxel_coord(pz[k]);
                    rec[k] = vox;
                    rb[k]  = (int)(vox >> 21);     // ix>>5 : 0..7
                    rv[k]  = true;
                    rrank[k] = atomicAdd(&s_cnt[rb[k]], 1u);
                }
            }
        }
        __syncthreads();

        if (tid == 0) {                   // 8-wide exclusive prefix
            u32 run = 0;
            #pragma unroll
            for (int b = 0; b < NBUCK; ++b) { s_off[b] = run; run += s_cnt[b]; }
        }
        if (tid < NBUCK)                  // reserve global space per bucket
            s_base[tid] = atomicAdd(&cursors[tid], s_cnt[tid]);
        __syncthreads();

        #pragma unroll
        for (int k = 0; k < 4; ++k)
            if (rv[k]) s_buf[s_off[rb[k]] + rrank[k]] = rec[k];
        __syncthreads();

        // coalesced copy-out per bucket
        for (int b = 0; b < NBUCK; ++b) {
            u32 cnt = s_cnt[b], off = s_off[b], gb = s_base[b];
            if (gb >= (u32)CAP) continue;          // overflow clamp (memory safety)
            u32 maxn = (u32)CAP - gb; if (cnt < maxn) maxn = cnt;
            for (u32 idx = tid; idx < maxn; idx += blockDim.x)
                buckets[(size_t)b * CAP + gb + idx] = s_buf[off + idx];
        }
        __syncthreads();
    }
}

// K2: group s (= blockIdx&7 -> XCD via round-robin) scatters ONLY bucket s
// into its 2 MB byte-grid slice. Per-XCD traffic: ~8 MB nt read + 2 MB
// L2-resident writes -> scattered-store HBM traffic collapses.
__global__ void k2_bucket_scatter(const u32* __restrict__ buckets,
                                  const u32* __restrict__ cursors,
                                  unsigned char* __restrict__ bgrid) {
    int s = blockIdx.x & 7;
    u32 cnt = cursors[s]; if (cnt > (u32)CAP) cnt = (u32)CAP;
    const u32* rec = buckets + (size_t)s * CAP;
    u32 g = (u32)((blockIdx.x >> 3) * blockDim.x + threadIdx.x);
    u32 stride = (u32)((gridDim.x >> 3) * blockDim.x);
    for (u32 j = g; j < cnt; j += stride) {
        u32 v = __builtin_nontemporal_load(&rec[j]);
        bgrid[v] = (unsigned char)1;     // v in [s*2MB, (s+1)*2MB)
    }
}

// K3: byte grid -> float grid (coalesced; doubles as zero-init of d_out).
__global__ void occ_expand(const uint4* __restrict__ bgrid16,
                           float4* __restrict__ grid4) {
    int i = blockIdx.x * blockDim.x + threadIdx.x;  // one thread = 16 voxels
    uint4 w = bgrid16[i];
    unsigned int ws[4] = {w.x, w.y, w.z, w.w};
    #pragma unroll
    for (int q = 0; q < 4; ++q) {
        unsigned int v = ws[q];
        float4 f;
        f.x = (v & 0x000000FFu) ? 1.0f : 0.0f;
        f.y = (v & 0x0000FF00u) ? 1.0f : 0.0f;
        f.z = (v & 0x00FF0000u) ? 1.0f : 0.0f;
        f.w = (v & 0xFF000000u) ? 1.0f : 0.0f;
        grid4[i * 4 + q] = f;
    }
}

// Fallback 1 (ws >= 16 MB): round-3 byte-grid scatter.
__global__ void occ_scatter_bytes(const vf4* __restrict__ pts4,
                                  const vf4* __restrict__ dens4,
                                  unsigned char* __restrict__ bgrid, int n4) {
    int t = blockIdx.x * blockDim.x + threadIdx.x;
    int stride = gridDim.x * blockDim.x;
    for (int i = t; i < n4; i += stride) {
        vf4 p0 = __builtin_nontemporal_load(&pts4[3 * i + 0]);
        vf4 p1 = __builtin_nontemporal_load(&pts4[3 * i + 1]);
        vf4 p2 = __builtin_nontemporal_load(&pts4[3 * i + 2]);
        vf4 d  = __builtin_nontemporal_load(&dens4[i]);
        float px[4] = {p0.x, p0.w, p1.z, p2.y};
        float py[4] = {p0.y, p1.x, p1.w, p2.z};
        float pz[4] = {p0.z, p1.y, p2.x, p2.w};
        float dd[4] = {d.x, d.y, d.z, d.w};
        #pragma unroll
        for (int k = 0; k < 4; ++k) {
            if (dd[k] > THRESH) {
                int ix = voxel_coord(px[k]);
                int iy = voxel_coord(py[k]);
                int iz = voxel_coord(pz[k]);
                bgrid[((ix << 8) | iy) * RES + iz] = (unsigned char)1;
            }
        }
    }
}

// Fallback 2 (tiny ws): round-1 direct float scatter.
__global__ void occ_scatter_float(const float4* __restrict__ pts4,
                                  const float4* __restrict__ dens4,
                                  float* __restrict__ grid, int n4) {
    int t = blockIdx.x * blockDim.x + threadIdx.x;
    int stride = gridDim.x * blockDim.x;
    for (int i = t; i < n4; i += stride) {
        float4 p0 = pts4[3 * i + 0];
        float4 p1 = pts4[3 * i + 1];
        float4 p2 = pts4[3 * i + 2];
        float4 d  = dens4[i];
        float px[4] = {p0.x, p0.w, p1.z, p2.y};
        float py[4] = {p0.y, p1.x, p1.w, p2.z};
        float pz[4] = {p0.z, p1.y, p2.x, p2.w};
        float dd[4] = {d.x, d.y, d.z, d.w};
        #pragma unroll
        for (int k = 0; k < 4; ++k) {
            if (dd[k] > THRESH) {
                int ix = voxel_coord(px[k]);
                int iy = voxel_coord(py[k]);
                int iz = voxel_coord(pz[k]);
                grid[((ix * RES) + iy) * RES + iz] = 1.0f;
            }
        }
    }
}

extern "C" void kernel_launch(void* const* d_in, const int* in_sizes, int n_in,
                              void* d_out, int out_size, void* d_ws, size_t ws_size,
                              hipStream_t stream) {
    const float* points    = (const float*)d_in[0];   // [N,3]
    const float* densities = (const float*)d_in[1];   // [N]
    float* grid = (float*)d_out;                      // 256^3 floats

    int n  = in_sizes[1];     // 16,000,000 (divisible by 16)
    int n4 = n / 4;

    // ws layout: [0,16MB) byte grid | [16MB,16MB+256) cursors | buckets 8xCAP u32
    const size_t OFF_CUR  = (size_t)GRID_VOX;
    const size_t OFF_BUCK = OFF_CUR + 256;
    const size_t need = OFF_BUCK + (size_t)NBUCK * CAP * sizeof(u32);  // 80,773,376

    if (ws_size >= need) {
        unsigned char* bgrid = (unsigned char*)d_ws;
        u32* cursors = (u32*)((char*)d_ws + OFF_CUR);
        u32* buckets = (u32*)((char*)d_ws + OFF_BUCK);

        // zero byte grid + cursors in one shot
        (void)hipMemsetAsync(d_ws, 0, OFF_BUCK, stream);

        k1_bin_records<<<2048, 256, 0, stream>>>(
            (const vf4*)points, (const vf4*)densities, buckets, cursors, n4);

        k2_bucket_scatter<<<2048, 256, 0, stream>>>(buckets, cursors, bgrid);

        occ_expand<<<GRID_VOX / (16 * 256), 256, 0, stream>>>(
            (const uint4*)bgrid, (float4*)grid);
    } else if (ws_size >= (size_t)GRID_VOX) {
        unsigned char* bgrid = (unsigned char*)d_ws;
        (void)hipMemsetAsync(d_ws, 0, (size_t)GRID_VOX, stream);
        occ_scatter_bytes<<<2048, 256, 0, stream>>>(
            (const vf4*)points, (const vf4*)densities, bgrid, n4);
        occ_expand<<<GRID_VOX / (16 * 256), 256, 0, stream>>>(
            (const uint4*)bgrid, (float4*)grid);
    } else {
        (void)hipMemsetAsync(d_out, 0, (size_t)out_size * sizeof(float), stream);
        occ_scatter_float<<<2048, 256, 0, stream>>>(
            (const float4*)points, (const float4*)densities, grid, n4);
    }
}

// Round 7
// 208.456 us; speedup vs baseline: 2.9539x; 1.4781x over previous
//
#include <hip/hip_runtime.h>

#define RES 256
#define THRESH 0.01f
#define GRID_VOX (RES * RES * RES)     // 16,777,216 voxels; byte grid = 16 MB
#define NBUCK 8                        // one bucket per ix-slice (ix>>5) -> XCD
#define CAP 1999616                    // per-bucket capacity (mean 1.984M + ~12 sigma)
#define CURS_STRIDE 64                 // u32s between cursors = 256 B (kill line contention)

typedef float vf4 __attribute__((ext_vector_type(4)));
typedef unsigned int u32;
typedef u32 vu4 __attribute__((ext_vector_type(4)));
typedef unsigned long long u64;

__device__ __forceinline__ int voxel_coord(float p) {
    // Replicate reference rounding exactly:
    // pts = -1 + p*2 ; coord = ((pts+1)/2)*256 ; trunc ; clamp
    float a = -1.0f + p * 2.0f;              // mul by 2 exact; one rounding
    float c = ((a + 1.0f) * 0.5f) * 256.0f;  // one rounding at (a+1); scalings exact
    int v = (int)c;
    v = v < 0 ? 0 : v;
    v = v > (RES - 1) ? (RES - 1) : v;
    return v;
}

// K1: inputs -> occupied voxel records binned into 8 ix-slice buckets.
// Wave-ballot counting (no per-record atomics), one block-level cursor
// reservation per iteration on 256B-padded cursors, direct global stores.
__global__ __launch_bounds__(256) void k1_bin(const vf4* __restrict__ pts4,
                                              const vf4* __restrict__ dens4,
                                              u32* __restrict__ buckets,
                                              u32* __restrict__ cursors,
                                              int n4, int niter) {
    __shared__ u32 wcnt[4][NBUCK];
    __shared__ u32 fbase[4][NBUCK];

    const int tid  = threadIdx.x;
    const int wid  = tid >> 6;
    const int lane = tid & 63;
    const int T    = gridDim.x * blockDim.x;
    const int t0   = blockIdx.x * blockDim.x + tid;
    const u64 lml  = (1ull << lane) - 1ull;

    for (int I = 0; I < niter; ++I) {
        u32 rec[16];
        u32 off16[16];
        u32 vbits = 0;

        // ---- load 4 quads (16 records) per thread ----
        #pragma unroll
        for (int s = 0; s < 4; ++s) {
            int q = t0 + (I * 4 + s) * T;
            if (q < n4) {
                vf4 p0 = __builtin_nontemporal_load(&pts4[3 * q + 0]);
                vf4 p1 = __builtin_nontemporal_load(&pts4[3 * q + 1]);
                vf4 p2 = __builtin_nontemporal_load(&pts4[3 * q + 2]);
                vf4 d  = __builtin_nontemporal_load(&dens4[q]);
                float px[4] = {p0.x, p0.w, p1.z, p2.y};
                float py[4] = {p0.y, p1.x, p1.w, p2.z};
                float pz[4] = {p0.z, p1.y, p2.x, p2.w};
                float dd[4] = {d.x, d.y, d.z, d.w};
                #pragma unroll
                for (int k = 0; k < 4; ++k) {
                    u32 vox = ((u32)voxel_coord(px[k]) << 16) |
                              ((u32)voxel_coord(py[k]) << 8)  |
                               (u32)voxel_coord(pz[k]);
                    rec[s * 4 + k] = vox;
                    if (dd[k] > THRESH) vbits |= 1u << (s * 4 + k);
                }
            } else {
                #pragma unroll
                for (int k = 0; k < 4; ++k) rec[s * 4 + k] = 0;
            }
        }

        // ---- wave-level counting via 4 ballots per record slot ----
        u32 run0 = 0, run1 = 0, run2 = 0, run3 = 0,
            run4 = 0, run5 = 0, run6 = 0, run7 = 0;
        #pragma unroll
        for (int kk = 0; kk < 16; ++kk) {
            u32 b = rec[kk] >> 21;
            bool val = (vbits >> kk) & 1u;
            u64 mv = __ballot(val);
            u64 m0 = __ballot(b & 1u);
            u64 m1 = __ballot(b & 2u);
            u64 m2 = __ballot(b & 4u);
            u64 A0 = mv & ~m2, A1 = mv & m2;
            u64 B00 = A0 & ~m1, B01 = A0 & m1, B10 = A1 & ~m1, B11 = A1 & m1;
            u64 M0 = B00 & ~m0, M1 = B00 & m0, M2 = B01 & ~m0, M3 = B01 & m0;
            u64 M4 = B10 & ~m0, M5 = B10 & m0, M6 = B11 & ~m0, M7 = B11 & m0;
            // lane's own bucket mask + rank within it
            u64 mm = (b & 4u) ? A1 : A0;
            mm &= (b & 2u) ? m1 : ~m1;
            mm &= (b & 1u) ? m0 : ~m0;
            u32 rank = (u32)__popcll(mm & lml);
            u32 runsel = b == 0 ? run0 : b == 1 ? run1 : b == 2 ? run2 :
                         b == 3 ? run3 : b == 4 ? run4 : b == 5 ? run5 :
                         b == 6 ? run6 : run7;
            off16[kk] = runsel + rank;
            run0 += (u32)__popcll(M0); run1 += (u32)__popcll(M1);
            run2 += (u32)__popcll(M2); run3 += (u32)__popcll(M3);
            run4 += (u32)__popcll(M4); run5 += (u32)__popcll(M5);
            run6 += (u32)__popcll(M6); run7 += (u32)__popcll(M7);
        }

        if (lane == 0) {
            wcnt[wid][0] = run0; wcnt[wid][1] = run1;
            wcnt[wid][2] = run2; wcnt[wid][3] = run3;
            wcnt[wid][4] = run4; wcnt[wid][5] = run5;
            wcnt[wid][6] = run6; wcnt[wid][7] = run7;
        }
        __syncthreads();

        // ---- one reservation per bucket per block (padded cursors) ----
        if (tid < NBUCK) {
            int b = tid;
            u32 c0 = wcnt[0][b], c1 = wcnt[1][b], c2 = wcnt[2][b], c3 = wcnt[3][b];
            u32 tot = c0 + c1 + c2 + c3;
            u32 gb = tot ? atomicAdd(&cursors[b * CURS_STRIDE], tot) : 0u;
            u32 base = (u32)b * (u32)CAP + gb;
            fbase[0][b] = base;
            fbase[1][b] = base + c0;
            fbase[2][b] = base + c0 + c1;
            fbase[3][b] = base + c0 + c1 + c2;
        }
        __syncthreads();

        // ---- direct global stores at reserved positions ----
        #pragma unroll
        for (int kk = 0; kk < 16; ++kk) {
            if ((vbits >> kk) & 1u) {
                u32 b = rec[kk] >> 21;
                u32 idx = fbase[wid][b] + off16[kk];   // LDS broadcast-ish read
                if (idx < 8u * (u32)CAP) buckets[idx] = rec[kk];
            }
        }
        __syncthreads();
    }
}

// K2: group s (= blockIdx&7 -> XCD via round-robin) scatters ONLY bucket s
// into its 2 MB byte-grid slice (L2-resident per XCD). uint4 record reads.
__global__ void k2_bucket_scatter(const u32* __restrict__ buckets,
                                  const u32* __restrict__ cursors,
                                  unsigned char* __restrict__ bgrid) {
    int s = blockIdx.x & 7;
    u32 cnt = cursors[s * CURS_STRIDE];
    if (cnt > (u32)CAP) cnt = (u32)CAP;
    const u32* rec = buckets + (size_t)s * CAP;
    u32 nq = cnt >> 2;
    u32 g = (u32)((blockIdx.x >> 3) * blockDim.x + threadIdx.x);
    u32 stride = (u32)((gridDim.x >> 3) * blockDim.x);
    for (u32 j = g; j < nq; j += stride) {
        vu4 r = __builtin_nontemporal_load((const vu4*)rec + j);
        bgrid[r.x & 0x00FFFFFFu] = (unsigned char)1;
        bgrid[r.y & 0x00FFFFFFu] = (unsigned char)1;
        bgrid[r.z & 0x00FFFFFFu] = (unsigned char)1;
        bgrid[r.w & 0x00FFFFFFu] = (unsigned char)1;
    }
    if ((blockIdx.x >> 3) == 0) {       // tail (cnt % 4)
        for (u32 j = (nq << 2) + threadIdx.x; j < cnt; j += blockDim.x)
            bgrid[rec[j] & 0x00FFFFFFu] = (unsigned char)1;
    }
}

// K3: byte grid -> float grid (coalesced; doubles as zero-init of d_out).
__global__ void occ_expand(const uint4* __restrict__ bgrid16,
                           float4* __restrict__ grid4) {
    int i = blockIdx.x * blockDim.x + threadIdx.x;  // one thread = 16 voxels
    uint4 w = bgrid16[i];
    unsigned int ws[4] = {w.x, w.y, w.z, w.w};
    #pragma unroll
    for (int q = 0; q < 4; ++q) {
        unsigned int v = ws[q];
        float4 f;
        f.x = (v & 0x000000FFu) ? 1.0f : 0.0f;
        f.y = (v & 0x0000FF00u) ? 1.0f : 0.0f;
        f.z = (v & 0x00FF0000u) ? 1.0f : 0.0f;
        f.w = (v & 0xFF000000u) ? 1.0f : 0.0f;
        grid4[i * 4 + q] = f;
    }
}

// Fallback 1 (ws >= 16 MB): round-3 byte-grid scatter.
__global__ void occ_scatter_bytes(const vf4* __restrict__ pts4,
                                  const vf4* __restrict__ dens4,
                                  unsigned char* __restrict__ bgrid, int n4) {
    int t = blockIdx.x * blockDim.x + threadIdx.x;
    int stride = gridDim.x * blockDim.x;
    for (int i = t; i < n4; i += stride) {
        vf4 p0 = __builtin_nontemporal_load(&pts4[3 * i + 0]);
        vf4 p1 = __builtin_nontemporal_load(&pts4[3 * i + 1]);
        vf4 p2 = __builtin_nontemporal_load(&pts4[3 * i + 2]);
        vf4 d  = __builtin_nontemporal_load(&dens4[i]);
        float px[4] = {p0.x, p0.w, p1.z, p2.y};
        float py[4] = {p0.y, p1.x, p1.w, p2.z};
        float pz[4] = {p0.z, p1.y, p2.x, p2.w};
        float dd[4] = {d.x, d.y, d.z, d.w};
        #pragma unroll
        for (int k = 0; k < 4; ++k) {
            if (dd[k] > THRESH) {
                int ix = voxel_coord(px[k]);
                int iy = voxel_coord(py[k]);
                int iz = voxel_coord(pz[k]);
                bgrid[((ix << 8) | iy) * RES + iz] = (unsigned char)1;
            }
        }
    }
}

// Fallback 2 (tiny ws): round-1 direct float scatter.
__global__ void occ_scatter_float(const float4* __restrict__ pts4,
                                  const float4* __restrict__ dens4,
                                  float* __restrict__ grid, int n4) {
    int t = blockIdx.x * blockDim.x + threadIdx.x;
    int stride = gridDim.x * blockDim.x;
    for (int i = t; i < n4; i += stride) {
        float4 p0 = pts4[3 * i + 0];
        float4 p1 = pts4[3 * i + 1];
        float4 p2 = pts4[3 * i + 2];
        float4 d  = dens4[i];
        float px[4] = {p0.x, p0.w, p1.z, p2.y};
        float py[4] = {p0.y, p1.x, p1.w, p2.z};
        float pz[4] = {p0.z, p1.y, p2.x, p2.w};
        float dd[4] = {d.x, d.y, d.z, d.w};
        #pragma unroll
        for (int k = 0; k < 4; ++k) {
            if (dd[k] > THRESH) {
                int ix = voxel_coord(px[k]);
                int iy = voxel_coord(py[k]);
                int iz = voxel_coord(pz[k]);
                grid[((ix * RES) + iy) * RES + iz] = 1.0f;
            }
        }
    }
}

extern "C" void kernel_launch(void* const* d_in, const int* in_sizes, int n_in,
                              void* d_out, int out_size, void* d_ws, size_t ws_size,
                              hipStream_t stream) {
    const float* points    = (const float*)d_in[0];   // [N,3]
    const float* densities = (const float*)d_in[1];   // [N]
    float* grid = (float*)d_out;                      // 256^3 floats

    int n  = in_sizes[1];     // 16,000,000 (divisible by 16)
    int n4 = n / 4;

    // ws layout: [0,16MB) byte grid | [16MB,+2KB) padded cursors | buckets 8xCAP u32
    const size_t OFF_CUR  = (size_t)GRID_VOX;
    const size_t OFF_BUCK = OFF_CUR + NBUCK * CURS_STRIDE * sizeof(u32);  // +2 KB
    const size_t need = OFF_BUCK + (size_t)NBUCK * CAP * sizeof(u32);     // 80,766,976

    if (ws_size >= need) {
        unsigned char* bgrid = (unsigned char*)d_ws;
        u32* cursors = (u32*)((char*)d_ws + OFF_CUR);
        u32* buckets = (u32*)((char*)d_ws + OFF_BUCK);

        // zero byte grid + cursor block in one shot
        (void)hipMemsetAsync(d_ws, 0, OFF_BUCK, stream);

        int T = 2048 * 256;
        int niter = (n4 + 4 * T - 1) / (4 * T);   // = 2 at N=16M
        k1_bin<<<2048, 256, 0, stream>>>(
            (const vf4*)points, (const vf4*)densities, buckets, cursors, n4, niter);

        k2_bucket_scatter<<<2048, 256, 0, stream>>>(buckets, cursors, bgrid);

        occ_expand<<<GRID_VOX / (16 * 256), 256, 0, stream>>>(
            (const uint4*)bgrid, (float4*)grid);
    } else if (ws_size >= (size_t)GRID_VOX) {
        unsigned char* bgrid = (unsigned char*)d_ws;
        (void)hipMemsetAsync(d_ws, 0, (size_t)GRID_VOX, stream);
        occ_scatter_bytes<<<2048, 256, 0, stream>>>(
            (const vf4*)points, (const vf4*)densities, bgrid, n4);
        occ_expand<<<GRID_VOX / (16 * 256), 256, 0, stream>>>(
            (const uint4*)bgrid, (float4*)grid);
    } else {
        (void)hipMemsetAsync(d_out, 0, (size_t)out_size * sizeof(float), stream);
        occ_scatter_float<<<2048, 256, 0, stream>>>(
            (const float4*)points, (const float4*)densities, grid, n4);
    }
}

// Round 8
// 144.279 us; speedup vs baseline: 4.2678x; 1.4448x over previous
//
#include <hip/hip_runtime.h>

#define RES 256
#define THRESH 0.01f
#define GRID_VOX (RES * RES * RES)   // 16,777,216
#define NB 256                       // buckets = ix value
#define CAPB 65536                   // per-bucket cap (mean 61.9K + ~14 sigma)
#define CSTRIDE 16                   // u32s between cursors = 64 B padding

typedef float vf4 __attribute__((ext_vector_type(4)));
typedef unsigned int u32;
typedef u32 vu4 __attribute__((ext_vector_type(4)));

__device__ __forceinline__ int voxel_coord(float p) {
    // Replicate reference rounding exactly:
    // pts = -1 + p*2 ; coord = ((pts+1)/2)*256 ; trunc ; clamp
    float a = -1.0f + p * 2.0f;              // mul by 2 exact; one rounding
    float c = ((a + 1.0f) * 0.5f) * 256.0f;  // one rounding at (a+1); scalings exact
    int v = (int)c;
    v = v < 0 ? 0 : v;
    v = v > (RES - 1) ? (RES - 1) : v;
    return v;
}

// K1: bin occupied voxel records into 256 ix-buckets.
// Per-record LDS atomicAdd rank (64 lanes over 256 counters: ~conflict-free),
// wave-0 shfl scan for block offsets, one padded global atomic per bucket,
// LDS-staged bucket-sorted copy-out (runs of ~16 -> coalesced).
__global__ __launch_bounds__(256) void k1_bin256(const vf4* __restrict__ pts4,
                                                 const vf4* __restrict__ dens4,
                                                 u32* __restrict__ buckets,
                                                 u32* __restrict__ cursors,
                                                 int n4, int niter) {
    __shared__ u32 s_cnt[NB];
    __shared__ u32 s_off[NB];
    __shared__ u32 s_base[NB];
    __shared__ u32 s_buf[4096];          // 256 threads * 16 records

    const int tid  = threadIdx.x;
    const int lane = tid & 63;
    const int wid  = tid >> 6;
    const int T    = gridDim.x * blockDim.x;
    const int t0   = blockIdx.x * blockDim.x + tid;

    for (int I = 0; I < niter; ++I) {
        s_cnt[tid] = 0;                  // 256 threads cover 256 counters
        __syncthreads();

        u32 rec[16], rnk[16], vbits = 0;

        #pragma unroll
        for (int s = 0; s < 4; ++s) {
            int q = t0 + (I * 4 + s) * T;
            if (q < n4) {
                vf4 p0 = __builtin_nontemporal_load(&pts4[3 * q + 0]);
                vf4 p1 = __builtin_nontemporal_load(&pts4[3 * q + 1]);
                vf4 p2 = __builtin_nontemporal_load(&pts4[3 * q + 2]);
                vf4 d  = __builtin_nontemporal_load(&dens4[q]);
                float px[4] = {p0.x, p0.w, p1.z, p2.y};
                float py[4] = {p0.y, p1.x, p1.w, p2.z};
                float pz[4] = {p0.z, p1.y, p2.x, p2.w};
                float dd[4] = {d.x, d.y, d.z, d.w};
                #pragma unroll
                for (int k = 0; k < 4; ++k) {
                    u32 vox = ((u32)voxel_coord(px[k]) << 16) |
                              ((u32)voxel_coord(py[k]) << 8)  |
                               (u32)voxel_coord(pz[k]);
                    int kk = s * 4 + k;
                    rec[kk] = vox;
                    if (dd[k] > THRESH) {
                        vbits |= 1u << kk;
                        rnk[kk] = atomicAdd(&s_cnt[vox >> 16], 1u);
                    }
                }
            }
        }
        __syncthreads();

        // exclusive scan of 256 counts: wave 0, 4 counters per lane
        if (wid == 0) {
            u32 c0 = s_cnt[4 * lane + 0], c1 = s_cnt[4 * lane + 1];
            u32 c2 = s_cnt[4 * lane + 2], c3 = s_cnt[4 * lane + 3];
            u32 w = c0 + c1 + c2 + c3;
            u32 x = w;
            #pragma unroll
            for (int dlt = 1; dlt < 64; dlt <<= 1) {
                u32 v = __shfl_up(x, dlt, 64);
                if (lane >= dlt) x += v;
            }
            u32 base = x - w;
            s_off[4 * lane + 0] = base;
            s_off[4 * lane + 1] = base + c0;
            s_off[4 * lane + 2] = base + c0 + c1;
            s_off[4 * lane + 3] = base + c0 + c1 + c2;
        }
        __syncthreads();

        // one reservation per bucket per block (64 B padded cursors)
        {
            u32 c = s_cnt[tid];
            s_base[tid] = c ? atomicAdd(&cursors[tid * CSTRIDE], c) : 0u;
        }
        __syncthreads();

        // stage bucket-sorted into LDS
        #pragma unroll
        for (int kk = 0; kk < 16; ++kk)
            if ((vbits >> kk) & 1u) {
                u32 b = rec[kk] >> 16;
                s_buf[s_off[b] + rnk[kk]] = rec[kk];
            }
        __syncthreads();

        // copy out: consecutive idx -> runs of ~16 per bucket (coalesced)
        u32 total = s_off[NB - 1] + s_cnt[NB - 1];
        for (u32 idx = tid; idx < total; idx += 256u) {
            u32 r = s_buf[idx];
            u32 b = r >> 16;
            u32 within = s_base[b] + (idx - s_off[b]);
            if (within < (u32)CAPB)
                buckets[(b << 16) + within] = r;   // CAPB == 65536
        }
        __syncthreads();
    }
}

// K2: one block per ix plane. Zero a 64 KB LDS byte plane, scatter this
// bucket's records into it (same-value byte races are safe), then write the
// whole plane to d_out as floats (fuses zero-init + expand; no byte grid).
__global__ __launch_bounds__(1024) void k2_plane(const u32* __restrict__ buckets,
                                                 const u32* __restrict__ cursors,
                                                 vf4* __restrict__ out4) {
    extern __shared__ unsigned char plane[];        // 65536 bytes
    const int ix  = blockIdx.x;
    const int tid = threadIdx.x;

    uint4* p16 = (uint4*)plane;
    #pragma unroll
    for (int j = 0; j < 4; ++j)                     // 4096 uint4 / 1024 thr
        p16[tid + j * 1024] = make_uint4(0u, 0u, 0u, 0u);
    __syncthreads();

    u32 cnt = cursors[ix * CSTRIDE];
    if (cnt > (u32)CAPB) cnt = (u32)CAPB;
    const u32* rec = buckets + ((u32)ix << 16);

    u32 nq = cnt >> 2;
    for (u32 j = tid; j < nq; j += 1024u) {
        vu4 r = __builtin_nontemporal_load((const vu4*)rec + j);
        plane[r.x & 0xFFFFu] = (unsigned char)1;
        plane[r.y & 0xFFFFu] = (unsigned char)1;
        plane[r.z & 0xFFFFu] = (unsigned char)1;
        plane[r.w & 0xFFFFu] = (unsigned char)1;
    }
    for (u32 j = (nq << 2) + tid; j < cnt; j += 1024u)
        plane[rec[j] & 0xFFFFu] = (unsigned char)1;
    __syncthreads();

    const u32* pw = (const u32*)plane;
    vf4* dst = out4 + ((size_t)ix << 14);           // 16384 float4 per plane
    #pragma unroll
    for (int j = 0; j < 16; ++j) {
        int i = tid + j * 1024;
        u32 w = pw[i];
        vf4 f;
        f.x = (w & 0x000000FFu) ? 1.0f : 0.0f;
        f.y = (w & 0x0000FF00u) ? 1.0f : 0.0f;
        f.z = (w & 0x00FF0000u) ? 1.0f : 0.0f;
        f.w = (w & 0xFF000000u) ? 1.0f : 0.0f;
        __builtin_nontemporal_store(f, &dst[i]);
    }
}

// Fallback 1 (ws >= 16 MB): byte-grid scatter + expand (round 3).
__global__ void occ_scatter_bytes(const vf4* __restrict__ pts4,
                                  const vf4* __restrict__ dens4,
                                  unsigned char* __restrict__ bgrid, int n4) {
    int t = blockIdx.x * blockDim.x + threadIdx.x;
    int stride = gridDim.x * blockDim.x;
    for (int i = t; i < n4; i += stride) {
        vf4 p0 = __builtin_nontemporal_load(&pts4[3 * i + 0]);
        vf4 p1 = __builtin_nontemporal_load(&pts4[3 * i + 1]);
        vf4 p2 = __builtin_nontemporal_load(&pts4[3 * i + 2]);
        vf4 d  = __builtin_nontemporal_load(&dens4[i]);
        float px[4] = {p0.x, p0.w, p1.z, p2.y};
        float py[4] = {p0.y, p1.x, p1.w, p2.z};
        float pz[4] = {p0.z, p1.y, p2.x, p2.w};
        float dd[4] = {d.x, d.y, d.z, d.w};
        #pragma unroll
        for (int k = 0; k < 4; ++k) {
            if (dd[k] > THRESH) {
                int ix = voxel_coord(px[k]);
                int iy = voxel_coord(py[k]);
                int iz = voxel_coord(pz[k]);
                bgrid[((ix << 8) | iy) * RES + iz] = (unsigned char)1;
            }
        }
    }
}

__global__ void occ_expand(const uint4* __restrict__ bgrid16,
                           float4* __restrict__ grid4) {
    int i = blockIdx.x * blockDim.x + threadIdx.x;
    uint4 w = bgrid16[i];
    unsigned int ws[4] = {w.x, w.y, w.z, w.w};
    #pragma unroll
    for (int q = 0; q < 4; ++q) {
        unsigned int v = ws[q];
        float4 f;
        f.x = (v & 0x000000FFu) ? 1.0f : 0.0f;
        f.y = (v & 0x0000FF00u) ? 1.0f : 0.0f;
        f.z = (v & 0x00FF0000u) ? 1.0f : 0.0f;
        f.w = (v & 0xFF000000u) ? 1.0f : 0.0f;
        grid4[i * 4 + q] = f;
    }
}

// Fallback 2 (tiny ws): direct float scatter (round 1).
__global__ void occ_scatter_float(const float4* __restrict__ pts4,
                                  const float4* __restrict__ dens4,
                                  float* __restrict__ grid, int n4) {
    int t = blockIdx.x * blockDim.x + threadIdx.x;
    int stride = gridDim.x * blockDim.x;
    for (int i = t; i < n4; i += stride) {
        float4 p0 = pts4[3 * i + 0];
        float4 p1 = pts4[3 * i + 1];
        float4 p2 = pts4[3 * i + 2];
        float4 d  = dens4[i];
        float px[4] = {p0.x, p0.w, p1.z, p2.y};
        float py[4] = {p0.y, p1.x, p1.w, p2.z};
        float pz[4] = {p0.z, p1.y, p2.x, p2.w};
        float dd[4] = {d.x, d.y, d.z, d.w};
        #pragma unroll
        for (int k = 0; k < 4; ++k) {
            if (dd[k] > THRESH) {
                int ix = voxel_coord(px[k]);
                int iy = voxel_coord(py[k]);
                int iz = voxel_coord(pz[k]);
                grid[((ix * RES) + iy) * RES + iz] = 1.0f;
            }
        }
    }
}

extern "C" void kernel_launch(void* const* d_in, const int* in_sizes, int n_in,
                              void* d_out, int out_size, void* d_ws, size_t ws_size,
                              hipStream_t stream) {
    const float* points    = (const float*)d_in[0];   // [N,3]
    const float* densities = (const float*)d_in[1];   // [N]
    float* grid = (float*)d_out;                      // 256^3 floats

    int n  = in_sizes[1];     // 16,000,000
    int n4 = n / 4;

    // ws layout: [0, 16 KB) padded cursors | [16 KB, +64 MB) buckets
    const size_t OFF_BUCK = (size_t)NB * CSTRIDE * sizeof(u32);           // 16 KB
    const size_t need = OFF_BUCK + (size_t)NB * CAPB * sizeof(u32);       // ~67.1 MB

    if (ws_size >= need) {
        u32* cursors = (u32*)d_ws;
        u32* buckets = (u32*)((char*)d_ws + OFF_BUCK);

        (void)hipMemsetAsync(d_ws, 0, OFF_BUCK, stream);   // cursors only (16 KB)

        const int BLK = 2048;
        int T = BLK * 256;
        int niter = (n4 + 4 * T - 1) / (4 * T);            // = 2 at N=16M
        k1_bin256<<<BLK, 256, 0, stream>>>(
            (const vf4*)points, (const vf4*)densities, buckets, cursors, n4, niter);

        k2_plane<<<NB, 1024, 65536, stream>>>(buckets, cursors, (vf4*)grid);
    } else if (ws_size >= (size_t)GRID_VOX) {
        unsigned char* bgrid = (unsigned char*)d_ws;
        (void)hipMemsetAsync(d_ws, 0, (size_t)GRID_VOX, stream);
        occ_scatter_bytes<<<2048, 256, 0, stream>>>(
            (const vf4*)points, (const vf4*)densities, bgrid, n4);
        occ_expand<<<GRID_VOX / (16 * 256), 256, 0, stream>>>(
            (const uint4*)bgrid, (float4*)grid);
    } else {
        (void)hipMemsetAsync(d_out, 0, (size_t)out_size * sizeof(float), stream);
        occ_scatter_float<<<2048, 256, 0, stream>>>(
            (const float4*)points, (const float4*)densities, grid, n4);
    }
}

// Round 9
// 130.871 us; speedup vs baseline: 4.7051x; 1.1025x over previous
//
#include <hip/hip_runtime.h>

#define RES 256
#define THRESH 0.01f
#define GRID_VOX (RES * RES * RES)   // 16,777,216
#define NB 256                       // buckets = ix value
#define CAPB 65536                   // per-bucket cap (mean 61.9K + ~14.7 sigma)
#define CSTRIDE 16                   // u32s between cursors = 64 B padding

typedef float vf4 __attribute__((ext_vector_type(4)));
typedef unsigned int u32;
typedef unsigned short u16;
typedef u32 vu4 __attribute__((ext_vector_type(4)));

__device__ __forceinline__ int voxel_coord(float p) {
    // Replicate reference rounding exactly:
    // pts = -1 + p*2 ; coord = ((pts+1)/2)*256 ; trunc ; clamp
    float a = -1.0f + p * 2.0f;              // mul by 2 exact; one rounding
    float c = ((a + 1.0f) * 0.5f) * 256.0f;  // one rounding at (a+1); scalings exact
    int v = (int)c;
    v = v < 0 ? 0 : v;
    v = v > (RES - 1) ? (RES - 1) : v;
    return v;
}

// K1: bin occupied voxels into 256 ix-buckets as 16-bit plane-local records.
// LDS atomicAdd rank, wave-0 shfl scan, one padded global atomic per bucket
// (concurrent with scan), LDS-staged sorted copy-out of ushort records.
__global__ __launch_bounds__(256) void k1_bin256(const vf4* __restrict__ pts4,
                                                 const vf4* __restrict__ dens4,
                                                 u16* __restrict__ buckets16,
                                                 u32* __restrict__ cursors,
                                                 int n4, int niter) {
    __shared__ u32 s_cnt[NB];
    __shared__ u32 s_off[NB];
    __shared__ u32 s_base[NB];
    __shared__ u32 s_buf[4096];          // staged u32 records (bucket in bits 16-23)

    const int tid  = threadIdx.x;
    const int lane = tid & 63;
    const int wid  = tid >> 6;
    const int T    = gridDim.x * blockDim.x;
    const int t0   = blockIdx.x * blockDim.x + tid;

    for (int I = 0; I < niter; ++I) {
        s_cnt[tid] = 0;
        __syncthreads();

        u32 rec[16], rnk[16], vbits = 0;

        #pragma unroll
        for (int h = 0; h < 2; ++h) {            // process 2 quads per batch
            vf4 P[2][3], D[2];
            u32 qm = 0;
            #pragma unroll
            for (int s2 = 0; s2 < 2; ++s2) {     // issue 8 loads before compute
                int q = t0 + (I * 4 + h * 2 + s2) * T;
                if (q < n4) {
                    qm |= 1u << s2;
                    P[s2][0] = __builtin_nontemporal_load(&pts4[3 * q + 0]);
                    P[s2][1] = __builtin_nontemporal_load(&pts4[3 * q + 1]);
                    P[s2][2] = __builtin_nontemporal_load(&pts4[3 * q + 2]);
                    D[s2]    = __builtin_nontemporal_load(&dens4[q]);
                }
            }
            #pragma unroll
            for (int s2 = 0; s2 < 2; ++s2) {
                if (!((qm >> s2) & 1u)) continue;
                float px[4] = {P[s2][0].x, P[s2][0].w, P[s2][1].z, P[s2][2].y};
                float py[4] = {P[s2][0].y, P[s2][1].x, P[s2][1].w, P[s2][2].z};
                float pz[4] = {P[s2][0].z, P[s2][1].y, P[s2][2].x, P[s2][2].w};
                float dd[4] = {D[s2].x, D[s2].y, D[s2].z, D[s2].w};
                #pragma unroll
                for (int k = 0; k < 4; ++k) {
                    int kk = (h * 2 + s2) * 4 + k;
                    u32 vox = ((u32)voxel_coord(px[k]) << 16) |
                              ((u32)voxel_coord(py[k]) << 8)  |
                               (u32)voxel_coord(pz[k]);
                    rec[kk] = vox;
                    if (dd[k] > THRESH) {
                        vbits |= 1u << kk;
                        rnk[kk] = atomicAdd(&s_cnt[vox >> 16], 1u);
                    }
                }
            }
        }
        __syncthreads();

        // reservation (all 256 tids, padded cursors) CONCURRENT with scan (wave 0)
        {
            u32 c = s_cnt[tid];
            s_base[tid] = c ? atomicAdd(&cursors[tid * CSTRIDE], c) : 0u;
        }
        if (wid == 0) {                          // exclusive scan of 256 counts
            u32 c0 = s_cnt[4 * lane + 0], c1 = s_cnt[4 * lane + 1];
            u32 c2 = s_cnt[4 * lane + 2], c3 = s_cnt[4 * lane + 3];
            u32 w = c0 + c1 + c2 + c3;
            u32 x = w;
            #pragma unroll
            for (int dlt = 1; dlt < 64; dlt <<= 1) {
                u32 v = __shfl_up(x, dlt, 64);
                if (lane >= dlt) x += v;
            }
            u32 base = x - w;
            s_off[4 * lane + 0] = base;
            s_off[4 * lane + 1] = base + c0;
            s_off[4 * lane + 2] = base + c0 + c1;
            s_off[4 * lane + 3] = base + c0 + c1 + c2;
        }
        __syncthreads();

        // stage bucket-sorted (u32, keeps bucket id for copy-out)
        #pragma unroll
        for (int kk = 0; kk < 16; ++kk)
            if ((vbits >> kk) & 1u) {
                u32 b = rec[kk] >> 16;
                s_buf[s_off[b] + rnk[kk]] = rec[kk];
            }
        __syncthreads();

        // copy out as ushort (halved record traffic), runs of ~16 per bucket
        u32 total = s_off[NB - 1] + s_cnt[NB - 1];
        for (u32 idx = tid; idx < total; idx += 256u) {
            u32 r = s_buf[idx];
            u32 b = r >> 16;
            u32 within = s_base[b] + (idx - s_off[b]);
            if (within < (u32)CAPB)
                buckets16[(b << 16) + within] = (u16)r;
        }
        __syncthreads();
    }
}

// K2: one block per ix plane. Zero 64 KB LDS byte plane, scatter this
// bucket's ushort records into it (same-value races safe), write the plane
// to d_out as floats (fuses zero-init + expand).
__global__ __launch_bounds__(1024) void k2_plane(const u16* __restrict__ buckets16,
                                                 const u32* __restrict__ cursors,
                                                 vf4* __restrict__ out4) {
    extern __shared__ unsigned char plane[];        // 65536 bytes
    const int ix  = blockIdx.x;
    const int tid = threadIdx.x;

    uint4* p16 = (uint4*)plane;
    #pragma unroll
    for (int j = 0; j < 4; ++j)                     // 4096 uint4 / 1024 thr
        p16[tid + j * 1024] = make_uint4(0u, 0u, 0u, 0u);
    __syncthreads();

    u32 cnt = cursors[ix * CSTRIDE];
    if (cnt > (u32)CAPB) cnt = (u32)CAPB;
    const u16* rec = buckets16 + ((size_t)ix << 16);

    u32 n8 = cnt >> 3;                              // 8 records per vu4 load
    for (u32 j = tid; j < n8; j += 1024u) {
        vu4 r = __builtin_nontemporal_load((const vu4*)rec + j);
        plane[r.x & 0xFFFFu] = (unsigned char)1; plane[r.x >> 16] = (unsigned char)1;
        plane[r.y & 0xFFFFu] = (unsigned char)1; plane[r.y >> 16] = (unsigned char)1;
        plane[r.z & 0xFFFFu] = (unsigned char)1; plane[r.z >> 16] = (unsigned char)1;
        plane[r.w & 0xFFFFu] = (unsigned char)1; plane[r.w >> 16] = (unsigned char)1;
    }
    for (u32 j = (n8 << 3) + tid; j < cnt; j += 1024u)
        plane[rec[j]] = (unsigned char)1;
    __syncthreads();

    const u32* pw = (const u32*)plane;
    vf4* dst = out4 + ((size_t)ix << 14);           // 16384 float4 per plane
    #pragma unroll
    for (int j = 0; j < 16; ++j) {
        int i = tid + j * 1024;
        u32 w = pw[i];
        vf4 f;
        f.x = (w & 0x000000FFu) ? 1.0f : 0.0f;
        f.y = (w & 0x0000FF00u) ? 1.0f : 0.0f;
        f.z = (w & 0x00FF0000u) ? 1.0f : 0.0f;
        f.w = (w & 0xFF000000u) ? 1.0f : 0.0f;
        __builtin_nontemporal_store(f, &dst[i]);
    }
}

// Fallback 1 (ws >= 16 MB): byte-grid scatter + expand (round 3).
__global__ void occ_scatter_bytes(const vf4* __restrict__ pts4,
                                  const vf4* __restrict__ dens4,
                                  unsigned char* __restrict__ bgrid, int n4) {
    int t = blockIdx.x * blockDim.x + threadIdx.x;
    int stride = gridDim.x * blockDim.x;
    for (int i = t; i < n4; i += stride) {
        vf4 p0 = __builtin_nontemporal_load(&pts4[3 * i + 0]);
        vf4 p1 = __builtin_nontemporal_load(&pts4[3 * i + 1]);
        vf4 p2 = __builtin_nontemporal_load(&pts4[3 * i + 2]);
        vf4 d  = __builtin_nontemporal_load(&dens4[i]);
        float px[4] = {p0.x, p0.w, p1.z, p2.y};
        float py[4] = {p0.y, p1.x, p1.w, p2.z};
        float pz[4] = {p0.z, p1.y, p2.x, p2.w};
        float dd[4] = {d.x, d.y, d.z, d.w};
        #pragma unroll
        for (int k = 0; k < 4; ++k) {
            if (dd[k] > THRESH) {
                int ix = voxel_coord(px[k]);
                int iy = voxel_coord(py[k]);
                int iz = voxel_coord(pz[k]);
                bgrid[((ix << 8) | iy) * RES + iz] = (unsigned char)1;
            }
        }
    }
}

__global__ void occ_expand(const uint4* __restrict__ bgrid16,
                           float4* __restrict__ grid4) {
    int i = blockIdx.x * blockDim.x + threadIdx.x;
    uint4 w = bgrid16[i];
    unsigned int ws[4] = {w.x, w.y, w.z, w.w};
    #pragma unroll
    for (int q = 0; q < 4; ++q) {
        unsigned int v = ws[q];
        float4 f;
        f.x = (v & 0x000000FFu) ? 1.0f : 0.0f;
        f.y = (v & 0x0000FF00u) ? 1.0f : 0.0f;
        f.z = (v & 0x00FF0000u) ? 1.0f : 0.0f;
        f.w = (v & 0xFF000000u) ? 1.0f : 0.0f;
        grid4[i * 4 + q] = f;
    }
}

// Fallback 2 (tiny ws): direct float scatter (round 1).
__global__ void occ_scatter_float(const float4* __restrict__ pts4,
                                  const float4* __restrict__ dens4,
                                  float* __restrict__ grid, int n4) {
    int t = blockIdx.x * blockDim.x + threadIdx.x;
    int stride = gridDim.x * blockDim.x;
    for (int i = t; i < n4; i += stride) {
        float4 p0 = pts4[3 * i + 0];
        float4 p1 = pts4[3 * i + 1];
        float4 p2 = pts4[3 * i + 2];
        float4 d  = dens4[i];
        float px[4] = {p0.x, p0.w, p1.z, p2.y};
        float py[4] = {p0.y, p1.x, p1.w, p2.z};
        float pz[4] = {p0.z, p1.y, p2.x, p2.w};
        float dd[4] = {d.x, d.y, d.z, d.w};
        #pragma unroll
        for (int k = 0; k < 4; ++k) {
            if (dd[k] > THRESH) {
                int ix = voxel_coord(px[k]);
                int iy = voxel_coord(py[k]);
                int iz = voxel_coord(pz[k]);
                grid[((ix * RES) + iy) * RES + iz] = 1.0f;
            }
        }
    }
}

extern "C" void kernel_launch(void* const* d_in, const int* in_sizes, int n_in,
                              void* d_out, int out_size, void* d_ws, size_t ws_size,
                              hipStream_t stream) {
    const float* points    = (const float*)d_in[0];   // [N,3]
    const float* densities = (const float*)d_in[1];   // [N]
    float* grid = (float*)d_out;                      // 256^3 floats

    int n  = in_sizes[1];     // 16,000,000
    int n4 = n / 4;

    // ws layout: [0, 16 KB) padded cursors | [16 KB, +32 MB) ushort buckets
    const size_t OFF_BUCK = (size_t)NB * CSTRIDE * sizeof(u32);           // 16 KB
    const size_t need = OFF_BUCK + (size_t)NB * CAPB * sizeof(u16);       // ~33.6 MB

    if (ws_size >= need) {
        u32* cursors  = (u32*)d_ws;
        u16* buckets16 = (u16*)((char*)d_ws + OFF_BUCK);

        (void)hipMemsetAsync(d_ws, 0, OFF_BUCK, stream);   // cursors only (16 KB)

        const int BLK = 2048;
        int T = BLK * 256;
        int niter = (n4 + 4 * T - 1) / (4 * T);            // = 2 at N=16M
        k1_bin256<<<BLK, 256, 0, stream>>>(
            (const vf4*)points, (const vf4*)densities, buckets16, cursors, n4, niter);

        k2_plane<<<NB, 1024, 65536, stream>>>(buckets16, cursors, (vf4*)grid);
    } else if (ws_size >= (size_t)GRID_VOX) {
        unsigned char* bgrid = (unsigned char*)d_ws;
        (void)hipMemsetAsync(d_ws, 0, (size_t)GRID_VOX, stream);
        occ_scatter_bytes<<<2048, 256, 0, stream>>>(
            (const vf4*)points, (const vf4*)densities, bgrid, n4);
        occ_expand<<<GRID_VOX / (16 * 256), 256, 0, stream>>>(
            (const uint4*)bgrid, (float4*)grid);
    } else {
        (void)hipMemsetAsync(d_out, 0, (size_t)out_size * sizeof(float), stream);
        occ_scatter_float<<<2048, 256, 0, stream>>>(
            (const float4*)points, (const float4*)densities, grid, n4);
    }
}

// Round 10
// 127.954 us; speedup vs baseline: 4.8124x; 1.0228x over previous
//
#include <hip/hip_runtime.h>

#define RES 256
#define THRESH 0.01f
#define GRID_VOX (RES * RES * RES)   // 16,777,216
#define NB 256                       // buckets = ix value
#define CHUNK_REC 4096               // max records per chunk (256 thr * 16)

typedef float vf4 __attribute__((ext_vector_type(4)));
typedef unsigned int u32;
typedef unsigned short u16;
typedef u32 vu4 __attribute__((ext_vector_type(4)));

__device__ __forceinline__ int voxel_coord(float p) {
    // Replicate reference rounding exactly:
    // pts = -1 + p*2 ; coord = ((pts+1)/2)*256 ; trunc ; clamp
    float a = -1.0f + p * 2.0f;              // mul by 2 exact; one rounding
    float c = ((a + 1.0f) * 0.5f) * 256.0f;  // one rounding at (a+1); scalings exact
    int v = (int)c;
    v = v < 0 ? 0 : v;
    v = v > (RES - 1) ? (RES - 1) : v;
    return v;
}

// K1: bin occupied voxels into 256 ix-buckets, chunk-private regions.
// ZERO global atomics: chunk c owns region [c*4096, (c+1)*4096) records and
// meta row meta[c*256 + b] = off | (cnt<<16). Copy-out is one contiguous
// coalesced burst of packed u16 pairs.
__global__ __launch_bounds__(256) void k1_bin256(const vf4* __restrict__ pts4,
                                                 const vf4* __restrict__ dens4,
                                                 u32* __restrict__ regions32,
                                                 u32* __restrict__ meta,
                                                 int n4, int niter) {
    __shared__ u32 s_cnt[NB];
    __shared__ u32 s_off[NB];
    __shared__ u32 s_buf[CHUNK_REC];

    const int tid  = threadIdx.x;
    const int lane = tid & 63;
    const int wid  = tid >> 6;
    const int T    = gridDim.x * blockDim.x;
    const int t0   = blockIdx.x * blockDim.x + tid;

    for (int I = 0; I < niter; ++I) {
        s_cnt[tid] = 0;
        __syncthreads();

        u32 rec[16], rnk[16], vbits = 0;

        #pragma unroll
        for (int h = 0; h < 2; ++h) {            // 2 batches of 2 quads
            vf4 P[2][3], D[2];
            u32 qm = 0;
            #pragma unroll
            for (int s2 = 0; s2 < 2; ++s2) {     // issue 8 loads before compute
                int q = t0 + (I * 4 + h * 2 + s2) * T;
                if (q < n4) {
                    qm |= 1u << s2;
                    P[s2][0] = __builtin_nontemporal_load(&pts4[3 * q + 0]);
                    P[s2][1] = __builtin_nontemporal_load(&pts4[3 * q + 1]);
                    P[s2][2] = __builtin_nontemporal_load(&pts4[3 * q + 2]);
                    D[s2]    = __builtin_nontemporal_load(&dens4[q]);
                }
            }
            #pragma unroll
            for (int s2 = 0; s2 < 2; ++s2) {
                if (!((qm >> s2) & 1u)) continue;
                float px[4] = {P[s2][0].x, P[s2][0].w, P[s2][1].z, P[s2][2].y};
                float py[4] = {P[s2][0].y, P[s2][1].x, P[s2][1].w, P[s2][2].z};
                float pz[4] = {P[s2][0].z, P[s2][1].y, P[s2][2].x, P[s2][2].w};
                float dd[4] = {D[s2].x, D[s2].y, D[s2].z, D[s2].w};
                #pragma unroll
                for (int k = 0; k < 4; ++k) {
                    int kk = (h * 2 + s2) * 4 + k;
                    u32 vox = ((u32)voxel_coord(px[k]) << 16) |
                              ((u32)voxel_coord(py[k]) << 8)  |
                               (u32)voxel_coord(pz[k]);
                    rec[kk] = vox;
                    if (dd[k] > THRESH) {
                        vbits |= 1u << kk;
                        rnk[kk] = atomicAdd(&s_cnt[vox >> 16], 1u);
                    }
                }
            }
        }
        __syncthreads();

        if (wid == 0) {                          // exclusive scan of 256 counts
            u32 c0 = s_cnt[4 * lane + 0], c1 = s_cnt[4 * lane + 1];
            u32 c2 = s_cnt[4 * lane + 2], c3 = s_cnt[4 * lane + 3];
            u32 w = c0 + c1 + c2 + c3;
            u32 x = w;
            #pragma unroll
            for (int dlt = 1; dlt < 64; dlt <<= 1) {
                u32 v = __shfl_up(x, dlt, 64);
                if (lane >= dlt) x += v;
            }
            u32 base = x - w;
            s_off[4 * lane + 0] = base;
            s_off[4 * lane + 1] = base + c0;
            s_off[4 * lane + 2] = base + c0 + c1;
            s_off[4 * lane + 3] = base + c0 + c1 + c2;
        }
        __syncthreads();

        const u32 c = (u32)I * gridDim.x + blockIdx.x;   // chunk id

        // meta row: coalesced 1 KB store per chunk (no atomics anywhere)
        meta[(size_t)c * NB + tid] = s_off[tid] | (s_cnt[tid] << 16);

        // stage bucket-sorted records in LDS
        #pragma unroll
        for (int kk = 0; kk < 16; ++kk)
            if ((vbits >> kk) & 1u) {
                u32 b = rec[kk] >> 16;
                s_buf[s_off[b] + rnk[kk]] = rec[kk];
            }
        __syncthreads();

        // copy-out: one contiguous coalesced burst of packed u16 pairs
        u32 total = s_off[NB - 1] + s_cnt[NB - 1];
        u32 nw = (total + 1) >> 1;
        u32* reg = regions32 + (size_t)c * (CHUNK_REC / 2);
        for (u32 idx = tid; idx < nw; idx += 256u) {
            u32 lo = s_buf[2 * idx] & 0xFFFFu;
            u32 hi = s_buf[2 * idx + 1] & 0xFFFFu;   // garbage past total: never read
            reg[idx] = lo | (hi << 16);
        }
        __syncthreads();                             // protect s_buf/s_cnt reuse
    }
}

// K2: one block per ix plane. Zero 64 KB LDS byte plane, gather each chunk's
// run for this plane (meta + records are LLC-hot from K1), scatter into LDS,
// write the plane to d_out as floats (fused zero-init + expand).
__global__ __launch_bounds__(1024) void k2_plane(const u16* __restrict__ regions16,
                                                 const u32* __restrict__ meta,
                                                 vf4* __restrict__ out4,
                                                 int nchunk) {
    extern __shared__ unsigned char plane[];        // 65536 bytes
    const int ix  = blockIdx.x;
    const int tid = threadIdx.x;

    uint4* p16 = (uint4*)plane;
    #pragma unroll
    for (int j = 0; j < 4; ++j)                     // 4096 uint4 / 1024 thr
        p16[tid + j * 1024] = make_uint4(0u, 0u, 0u, 0u);
    __syncthreads();

    for (int c = tid; c < nchunk; c += 1024) {
        u32 m = meta[(size_t)c * NB + ix];
        u32 off = m & 0xFFFFu;
        u32 cnt = m >> 16;
        const u16* run = regions16 + (size_t)c * CHUNK_REC + off;
        for (u32 j = 0; j < cnt; ++j)
            plane[run[j]] = (unsigned char)1;       // same-value races safe
    }
    __syncthreads();

    const u32* pw = (const u32*)plane;
    vf4* dst = out4 + ((size_t)ix << 14);           // 16384 float4 per plane
    #pragma unroll
    for (int j = 0; j < 16; ++j) {
        int i = tid + j * 1024;
        u32 w = pw[i];
        vf4 f;
        f.x = (w & 0x000000FFu) ? 1.0f : 0.0f;
        f.y = (w & 0x0000FF00u) ? 1.0f : 0.0f;
        f.z = (w & 0x00FF0000u) ? 1.0f : 0.0f;
        f.w = (w & 0xFF000000u) ? 1.0f : 0.0f;
        __builtin_nontemporal_store(f, &dst[i]);
    }
}

// Fallback 1 (ws >= 16 MB): byte-grid scatter + expand (round 3).
__global__ void occ_scatter_bytes(const vf4* __restrict__ pts4,
                                  const vf4* __restrict__ dens4,
                                  unsigned char* __restrict__ bgrid, int n4) {
    int t = blockIdx.x * blockDim.x + threadIdx.x;
    int stride = gridDim.x * blockDim.x;
    for (int i = t; i < n4; i += stride) {
        vf4 p0 = __builtin_nontemporal_load(&pts4[3 * i + 0]);
        vf4 p1 = __builtin_nontemporal_load(&pts4[3 * i + 1]);
        vf4 p2 = __builtin_nontemporal_load(&pts4[3 * i + 2]);
        vf4 d  = __builtin_nontemporal_load(&dens4[i]);
        float px[4] = {p0.x, p0.w, p1.z, p2.y};
        float py[4] = {p0.y, p1.x, p1.w, p2.z};
        float pz[4] = {p0.z, p1.y, p2.x, p2.w};
        float dd[4] = {d.x, d.y, d.z, d.w};
        #pragma unroll
        for (int k = 0; k < 4; ++k) {
            if (dd[k] > THRESH) {
                int ix = voxel_coord(px[k]);
                int iy = voxel_coord(py[k]);
                int iz = voxel_coord(pz[k]);
                bgrid[((ix << 8) | iy) * RES + iz] = (unsigned char)1;
            }
        }
    }
}

__global__ void occ_expand(const uint4* __restrict__ bgrid16,
                           float4* __restrict__ grid4) {
    int i = blockIdx.x * blockDim.x + threadIdx.x;
    uint4 w = bgrid16[i];
    unsigned int ws[4] = {w.x, w.y, w.z, w.w};
    #pragma unroll
    for (int q = 0; q < 4; ++q) {
        unsigned int v = ws[q];
        float4 f;
        f.x = (v & 0x000000FFu) ? 1.0f : 0.0f;
        f.y = (v & 0x0000FF00u) ? 1.0f : 0.0f;
        f.z = (v & 0x00FF0000u) ? 1.0f : 0.0f;
        f.w = (v & 0xFF000000u) ? 1.0f : 0.0f;
        grid4[i * 4 + q] = f;
    }
}

// Fallback 2 (tiny ws): direct float scatter (round 1).
__global__ void occ_scatter_float(const float4* __restrict__ pts4,
                                  const float4* __restrict__ dens4,
                                  float* __restrict__ grid, int n4) {
    int t = blockIdx.x * blockDim.x + threadIdx.x;
    int stride = gridDim.x * blockDim.x;
    for (int i = t; i < n4; i += stride) {
        float4 p0 = pts4[3 * i + 0];
        float4 p1 = pts4[3 * i + 1];
        float4 p2 = pts4[3 * i + 2];
        float4 d  = dens4[i];
        float px[4] = {p0.x, p0.w, p1.z, p2.y};
        float py[4] = {p0.y, p1.x, p1.w, p2.z};
        float pz[4] = {p0.z, p1.y, p2.x, p2.w};
        float dd[4] = {d.x, d.y, d.z, d.w};
        #pragma unroll
        for (int k = 0; k < 4; ++k) {
            if (dd[k] > THRESH) {
                int ix = voxel_coord(px[k]);
                int iy = voxel_coord(py[k]);
                int iz = voxel_coord(pz[k]);
                grid[((ix * RES) + iy) * RES + iz] = 1.0f;
            }
        }
    }
}

extern "C" void kernel_launch(void* const* d_in, const int* in_sizes, int n_in,
                              void* d_out, int out_size, void* d_ws, size_t ws_size,
                              hipStream_t stream) {
    const float* points    = (const float*)d_in[0];   // [N,3]
    const float* densities = (const float*)d_in[1];   // [N]
    float* grid = (float*)d_out;                      // 256^3 floats

    int n  = in_sizes[1];     // 16,000,000
    int n4 = n / 4;

    const int BLK = 2048;
    int T = BLK * 256;
    int niter  = (n4 + 4 * T - 1) / (4 * T);          // = 2 at N=16M
    int nchunk = BLK * niter;                         // 4096

    // ws layout: [0, metaSize) meta u32[nchunk*256] | regions u16[nchunk*4096]
    size_t metaSize = (size_t)nchunk * NB * sizeof(u32);          // 4 MB
    size_t need = metaSize + (size_t)nchunk * CHUNK_REC * sizeof(u16);  // 36 MB

    if (ws_size >= need) {
        u32* meta      = (u32*)d_ws;
        u32* regions32 = (u32*)((char*)d_ws + metaSize);
        const u16* regions16 = (const u16*)regions32;

        // no memset needed: meta fully written by K1, regions bounded by meta
        k1_bin256<<<BLK, 256, 0, stream>>>(
            (const vf4*)points, (const vf4*)densities, regions32, meta, n4, niter);

        k2_plane<<<NB, 1024, 65536, stream>>>(regions16, meta, (vf4*)grid, nchunk);
    } else if (ws_size >= (size_t)GRID_VOX) {
        unsigned char* bgrid = (unsigned char*)d_ws;
        (void)hipMemsetAsync(d_ws, 0, (size_t)GRID_VOX, stream);
        occ_scatter_bytes<<<2048, 256, 0, stream>>>(
            (const vf4*)points, (const vf4*)densities, bgrid, n4);
        occ_expand<<<GRID_VOX / (16 * 256), 256, 0, stream>>>(
            (const uint4*)bgrid, (float4*)grid);
    } else {
        (void)hipMemsetAsync(d_out, 0, (size_t)out_size * sizeof(float), stream);
        occ_scatter_float<<<2048, 256, 0, stream>>>(
            (const float4*)points, (const float4*)densities, grid, n4);
    }
}

// Round 11
// 107.352 us; speedup vs baseline: 5.7359x; 1.1919x over previous
//
#include <hip/hip_runtime.h>

#define RES 256
#define THRESH 0.01f
#define GRID_VOX (RES * RES * RES)   // 16,777,216
#define NB 256                       // buckets = ix value
#define CHUNK_REC 8192               // max records per chunk (256 thr * 32)
#define K1_BLOCKS 2048
#define QPT 8                        // quads per thread (32 records)

typedef float vf4 __attribute__((ext_vector_type(4)));
typedef unsigned int u32;
typedef unsigned short u16;
typedef u32 vu4 __attribute__((ext_vector_type(4)));

__device__ __forceinline__ int voxel_coord(float p) {
    // Replicate reference rounding exactly:
    // pts = -1 + p*2 ; coord = ((pts+1)/2)*256 ; trunc ; clamp
    float a = -1.0f + p * 2.0f;              // mul by 2 exact; one rounding
    float c = ((a + 1.0f) * 0.5f) * 256.0f;  // one rounding at (a+1); scalings exact
    int v = (int)c;
    v = v < 0 ? 0 : v;
    v = v > (RES - 1) ? (RES - 1) : v;
    return v;
}

// K1: single-iteration binning. 32 records/thread, 5 barriers/block total
// (vs 10), 16 loads in flight per batch. Chunk-private output regions, no
// global atomics, no memset. meta[c*256+b] = off | (cnt<<16).
__global__ __launch_bounds__(256) void k1_bin256(const vf4* __restrict__ pts4,
                                                 const vf4* __restrict__ dens4,
                                                 u32* __restrict__ regions32,
                                                 u32* __restrict__ meta,
                                                 int n4) {
    __shared__ u32 s_cnt[NB];
    __shared__ u32 s_off[NB];
    __shared__ u32 s_buf[CHUNK_REC];     // 32 KB staged records

    const int tid  = threadIdx.x;
    const int lane = tid & 63;
    const int wid  = tid >> 6;
    const int T    = gridDim.x * blockDim.x;
    const int t0   = blockIdx.x * blockDim.x + tid;

    s_cnt[tid] = 0;
    __syncthreads();

    u32 rec[QPT * 4], rnk[QPT * 4], vbits = 0;

    #pragma unroll
    for (int h = 0; h < 2; ++h) {                // 2 batches of 4 quads
        vf4 P[4][3], D[4];
        u32 qm = 0;
        #pragma unroll
        for (int s2 = 0; s2 < 4; ++s2) {         // 16 loads in flight
            int q = t0 + (h * 4 + s2) * T;
            if (q < n4) {
                qm |= 1u << s2;
                P[s2][0] = __builtin_nontemporal_load(&pts4[3 * q + 0]);
                P[s2][1] = __builtin_nontemporal_load(&pts4[3 * q + 1]);
                P[s2][2] = __builtin_nontemporal_load(&pts4[3 * q + 2]);
                D[s2]    = __builtin_nontemporal_load(&dens4[q]);
            }
        }
        #pragma unroll
        for (int s2 = 0; s2 < 4; ++s2) {
            if (!((qm >> s2) & 1u)) continue;
            float px[4] = {P[s2][0].x, P[s2][0].w, P[s2][1].z, P[s2][2].y};
            float py[4] = {P[s2][0].y, P[s2][1].x, P[s2][1].w, P[s2][2].z};
            float pz[4] = {P[s2][0].z, P[s2][1].y, P[s2][2].x, P[s2][2].w};
            float dd[4] = {D[s2].x, D[s2].y, D[s2].z, D[s2].w};
            #pragma unroll
            for (int k = 0; k < 4; ++k) {
                int kk = (h * 4 + s2) * 4 + k;
                u32 vox = ((u32)voxel_coord(px[k]) << 16) |
                          ((u32)voxel_coord(py[k]) << 8)  |
                           (u32)voxel_coord(pz[k]);
                rec[kk] = vox;
                if (dd[k] > THRESH) {
                    vbits |= 1u << kk;
                    rnk[kk] = atomicAdd(&s_cnt[vox >> 16], 1u);
                }
            }
        }
    }
    __syncthreads();

    if (wid == 0) {                              // exclusive scan of 256 counts
        u32 c0 = s_cnt[4 * lane + 0], c1 = s_cnt[4 * lane + 1];
        u32 c2 = s_cnt[4 * lane + 2], c3 = s_cnt[4 * lane + 3];
        u32 w = c0 + c1 + c2 + c3;
        u32 x = w;
        #pragma unroll
        for (int dlt = 1; dlt < 64; dlt <<= 1) {
            u32 v = __shfl_up(x, dlt, 64);
            if (lane >= dlt) x += v;
        }
        u32 base = x - w;
        s_off[4 * lane + 0] = base;
        s_off[4 * lane + 1] = base + c0;
        s_off[4 * lane + 2] = base + c0 + c1;
        s_off[4 * lane + 3] = base + c0 + c1 + c2;
    }
    __syncthreads();

    const u32 c = blockIdx.x;                    // chunk id == block

    // meta row: coalesced 1 KB store per chunk
    meta[(size_t)c * NB + tid] = s_off[tid] | (s_cnt[tid] << 16);

    // stage bucket-sorted records in LDS
    #pragma unroll
    for (int kk = 0; kk < QPT * 4; ++kk)
        if ((vbits >> kk) & 1u) {
            u32 b = rec[kk] >> 16;
            s_buf[s_off[b] + rnk[kk]] = rec[kk];
        }
    __syncthreads();

    // copy-out: one contiguous coalesced burst of packed u16 pairs
    u32 total = s_off[NB - 1] + s_cnt[NB - 1];
    u32 nw = (total + 1) >> 1;
    u32* reg = regions32 + (size_t)c * (CHUNK_REC / 2);
    for (u32 idx = tid; idx < nw; idx += 256u) {
        u32 lo = s_buf[2 * idx] & 0xFFFFu;
        u32 hi = s_buf[2 * idx + 1] & 0xFFFFu;   // garbage past total: never read
        reg[idx] = lo | (hi << 16);
    }
}

// K2: one block per ix plane. Zero 64 KB LDS byte plane, gather each chunk's
// run for this plane, scatter into LDS, write plane as floats (fused
// zero-init + expand).
__global__ __launch_bounds__(1024) void k2_plane(const u16* __restrict__ regions16,
                                                 const u32* __restrict__ meta,
                                                 vf4* __restrict__ out4,
                                                 int nchunk) {
    extern __shared__ unsigned char plane[];        // 65536 bytes
    const int ix  = blockIdx.x;
    const int tid = threadIdx.x;

    uint4* p16 = (uint4*)plane;
    #pragma unroll
    for (int j = 0; j < 4; ++j)                     // 4096 uint4 / 1024 thr
        p16[tid + j * 1024] = make_uint4(0u, 0u, 0u, 0u);
    __syncthreads();

    for (int c = tid; c < nchunk; c += 1024) {
        u32 m = meta[(size_t)c * NB + ix];
        u32 off = m & 0xFFFFu;
        u32 cnt = m >> 16;
        const u16* run = regions16 + (size_t)c * CHUNK_REC + off;
        for (u32 j = 0; j < cnt; ++j)
            plane[run[j]] = (unsigned char)1;       // same-value races safe
    }
    __syncthreads();

    const u32* pw = (const u32*)plane;
    vf4* dst = out4 + ((size_t)ix << 14);           // 16384 float4 per plane
    #pragma unroll
    for (int j = 0; j < 16; ++j) {
        int i = tid + j * 1024;
        u32 w = pw[i];
        vf4 f;
        f.x = (w & 0x000000FFu) ? 1.0f : 0.0f;
        f.y = (w & 0x0000FF00u) ? 1.0f : 0.0f;
        f.z = (w & 0x00FF0000u) ? 1.0f : 0.0f;
        f.w = (w & 0xFF000000u) ? 1.0f : 0.0f;
        __builtin_nontemporal_store(f, &dst[i]);
    }
}

// Fallback 1 (ws >= 16 MB): byte-grid scatter + expand (round 3).
__global__ void occ_scatter_bytes(const vf4* __restrict__ pts4,
                                  const vf4* __restrict__ dens4,
                                  unsigned char* __restrict__ bgrid, int n4) {
    int t = blockIdx.x * blockDim.x + threadIdx.x;
    int stride = gridDim.x * blockDim.x;
    for (int i = t; i < n4; i += stride) {
        vf4 p0 = __builtin_nontemporal_load(&pts4[3 * i + 0]);
        vf4 p1 = __builtin_nontemporal_load(&pts4[3 * i + 1]);
        vf4 p2 = __builtin_nontemporal_load(&pts4[3 * i + 2]);
        vf4 d  = __builtin_nontemporal_load(&dens4[i]);
        float px[4] = {p0.x, p0.w, p1.z, p2.y};
        float py[4] = {p0.y, p1.x, p1.w, p2.z};
        float pz[4] = {p0.z, p1.y, p2.x, p2.w};
        float dd[4] = {d.x, d.y, d.z, d.w};
        #pragma unroll
        for (int k = 0; k < 4; ++k) {
            if (dd[k] > THRESH) {
                int ix = voxel_coord(px[k]);
                int iy = voxel_coord(py[k]);
                int iz = voxel_coord(pz[k]);
                bgrid[((ix << 8) | iy) * RES + iz] = (unsigned char)1;
            }
        }
    }
}

__global__ void occ_expand(const uint4* __restrict__ bgrid16,
                           float4* __restrict__ grid4) {
    int i = blockIdx.x * blockDim.x + threadIdx.x;
    uint4 w = bgrid16[i];
    unsigned int ws[4] = {w.x, w.y, w.z, w.w};
    #pragma unroll
    for (int q = 0; q < 4; ++q) {
        unsigned int v = ws[q];
        float4 f;
        f.x = (v & 0x000000FFu) ? 1.0f : 0.0f;
        f.y = (v & 0x0000FF00u) ? 1.0f : 0.0f;
        f.z = (v & 0x00FF0000u) ? 1.0f : 0.0f;
        f.w = (v & 0xFF000000u) ? 1.0f : 0.0f;
        grid4[i * 4 + q] = f;
    }
}

// Fallback 2 (tiny ws): direct float scatter (round 1).
__global__ void occ_scatter_float(const float4* __restrict__ pts4,
                                  const float4* __restrict__ dens4,
                                  float* __restrict__ grid, int n4) {
    int t = blockIdx.x * blockDim.x + threadIdx.x;
    int stride = gridDim.x * blockDim.x;
    for (int i = t; i < n4; i += stride) {
        float4 p0 = pts4[3 * i + 0];
        float4 p1 = pts4[3 * i + 1];
        float4 p2 = pts4[3 * i + 2];
        float4 d  = dens4[i];
        float px[4] = {p0.x, p0.w, p1.z, p2.y};
        float py[4] = {p0.y, p1.x, p1.w, p2.z};
        float pz[4] = {p0.z, p1.y, p2.x, p2.w};
        float dd[4] = {d.x, d.y, d.z, d.w};
        #pragma unroll
        for (int k = 0; k < 4; ++k) {
            if (dd[k] > THRESH) {
                int ix = voxel_coord(px[k]);
                int iy = voxel_coord(py[k]);
                int iz = voxel_coord(pz[k]);
                grid[((ix * RES) + iy) * RES + iz] = 1.0f;
            }
        }
    }
}

extern "C" void kernel_launch(void* const* d_in, const int* in_sizes, int n_in,
                              void* d_out, int out_size, void* d_ws, size_t ws_size,
                              hipStream_t stream) {
    const float* points    = (const float*)d_in[0];   // [N,3]
    const float* densities = (const float*)d_in[1];   // [N]
    float* grid = (float*)d_out;                      // 256^3 floats

    int n  = in_sizes[1];     // 16,000,000
    int n4 = n / 4;

    const int nchunk = K1_BLOCKS;                     // 2048 (one chunk per block)

    // ws layout: [0, metaSize) meta u32[nchunk*256] | regions u16[nchunk*8192]
    size_t metaSize = (size_t)nchunk * NB * sizeof(u32);                // 2 MB
    size_t need = metaSize + (size_t)nchunk * CHUNK_REC * sizeof(u16);  // 34 MB

    // capacity check: K1 grid must cover all quads in one pass
    bool covered = (size_t)K1_BLOCKS * 256 * QPT >= (size_t)n4;

    if (ws_size >= need && covered) {
        u32* meta      = (u32*)d_ws;
        u32* regions32 = (u32*)((char*)d_ws + metaSize);
        const u16* regions16 = (const u16*)regions32;

        // no memset needed: meta fully written by K1, regions bounded by meta
        k1_bin256<<<K1_BLOCKS, 256, 0, stream>>>(
            (const vf4*)points, (const vf4*)densities, regions32, meta, n4);

        k2_plane<<<NB, 1024, 65536, stream>>>(regions16, meta, (vf4*)grid, nchunk);
    } else if (ws_size >= (size_t)GRID_VOX) {
        unsigned char* bgrid = (unsigned char*)d_ws;
        (void)hipMemsetAsync(d_ws, 0, (size_t)GRID_VOX, stream);
        occ_scatter_bytes<<<2048, 256, 0, stream>>>(
            (const vf4*)points, (const vf4*)densities, bgrid, n4);
        occ_expand<<<GRID_VOX / (16 * 256), 256, 0, stream>>>(
            (const uint4*)bgrid, (float4*)grid);
    } else {
        (void)hipMemsetAsync(d_out, 0, (size_t)out_size * sizeof(float), stream);
        occ_scatter_float<<<2048, 256, 0, stream>>>(
            (const float4*)points, (const float4*)densities, grid, n4);
    }
}